// Round 1
// 281.180 us; speedup vs baseline: 1.0555x; 1.0555x over previous
//
#include <hip/hip_runtime.h>
#include <cstdint>
#include <cstddef>

#define BN_INV 0.9999950000374997f  /* 1/sqrt(1+1e-5) */

typedef __attribute__((ext_vector_type(8))) _Float16 h8v;
typedef __attribute__((ext_vector_type(4))) float f4v;

// split v = hi + lo, both fp16; residual <= 2^-22 * |v|
__device__ __forceinline__ void fsplit(float v, ushort& h, ushort& l) {
    _Float16 hh = (_Float16)v;
    _Float16 ll = (_Float16)(v - (float)hh);
    h = __builtin_bit_cast(ushort, hh);
    l = __builtin_bit_cast(ushort, ll);
}

// ---------------------------------------------------------------------------
// Repack helper: (O,I,3,3) fp32 -> split fp16 hi/lo planes, A-frag order.
// dst[(ocg*NCH+chunk)*2*18432 + comp*18432 + tap*2048 + q*512 + oc*8 + j],
// ic = chunk*32 + q*8 + j
// ---------------------------------------------------------------------------
__device__ __forceinline__ void repack_one(
    const float* __restrict__ w, ushort* __restrict__ dst, int CIN, int i)
{
    int ocf = i / (CIN * 9);
    int r = i % (CIN * 9);
    int ic = r / 9;
    int tap = r % 9;
    int ocg = ocf >> 6, oc = ocf & 63;
    int chunk = ic >> 5, q = (ic >> 3) & 3, j = ic & 7;
    int nch = CIN >> 5;
    ushort h, l;
    fsplit(w[i], h, l);
    size_t base = (size_t)((ocg * nch + chunk) * 2) * 18432
                + (size_t)tap * 2048 + q * 512 + oc * 8 + j;
    dst[base] = h;
    dst[base + 18432] = l;
}

// ---------------------------------------------------------------------------
// Fused prep + conv1.
// Blocks 0..15: build U. 16..1527: repack w2/w3/w4.
// Blocks 1528..3575: conv1 (1->32, 256x256) + BN + ReLU -> e1 fp32,
// fused 2x2 pool -> split fp16 channel-last pt1 [b][128][128][hi32|lo32].
// Tile is 32 wide x 8 tall so each wave (2 rows x 32 px) stores full 128 B
// rows of e1 per instruction.
// ---------------------------------------------------------------------------
__global__ __launch_bounds__(256) void prep_conv1_kernel(
    const float* __restrict__ w0, const float* __restrict__ w1,
    float* __restrict__ U,
    const float* __restrict__ w2, ushort* __restrict__ wb2,
    const float* __restrict__ w3, ushort* __restrict__ wb3,
    const float* __restrict__ w4, ushort* __restrict__ wb4,
    const float* __restrict__ x, const float* __restrict__ wt,
    const float* __restrict__ g, const float* __restrict__ be,
    float* __restrict__ out, ushort* __restrict__ pooled)
{
    __shared__ float s_in[10][34];
    __shared__ float s_w[288];

    int blk = blockIdx.x;
    int tid = threadIdx.x;

    if (blk < 1528) {
        if (blk >= 376)      { repack_one(w4, wb4, 128, (blk - 376) * 256 + tid); return; }
        if (blk >= 88)       { repack_one(w3, wb3,  64, (blk -  88) * 256 + tid); return; }
        if (blk >= 16)       { repack_one(w2, wb2,  32, (blk -  16) * 256 + tid); return; }

        int idx = blk * 256 + tid;  // = c*16 + r
        int c = idx >> 4, r = idx & 15;
        float gr[4][2][2], gi[4][2][2];
        const float inv_sq2 = 0.70710678118654752f;
#pragma unroll
        for (int w = 0; w < 4; ++w) {
            float ty = w0[c * 2 + (w & 1)];
            float tz = w1[c * 2 + (w & 1)];
            float cy = cosf(0.5f * ty), sy = sinf(0.5f * ty);
            float cz = cosf(0.5f * tz), sz = sinf(0.5f * tz);
            float r00 = (cy - sy) * inv_sq2, r01 = (cy + sy) * inv_sq2;
            float r10 = (cy + sy) * inv_sq2, r11 = (sy - cy) * inv_sq2;
            gr[w][0][0] = cz * r00; gi[w][0][0] = -sz * r00;
            gr[w][0][1] = cz * r01; gi[w][0][1] = -sz * r01;
            gr[w][1][0] = cz * r10; gi[w][1][0] =  sz * r10;
            gr[w][1][1] = cz * r11; gi[w][1][1] =  sz * r11;
        }
        const int PTOT[16] = {0,13,3,14,6,11,5,8,12,1,15,2,10,7,9,4};
        int rp = PTOT[r];
        float* Uo = U + (size_t)c * 512 + r * 32;
#pragma unroll
        for (int cc = 0; cc < 16; ++cc) {
            float pr = 1.f, pi = 0.f;
#pragma unroll
            for (int w = 0; w < 4; ++w) {
                int ib = (rp >> (3 - w)) & 1, jb = (cc >> (3 - w)) & 1;
                float ar = gr[w][ib][jb], ai = gi[w][ib][jb];
                float nr = pr * ar - pi * ai;
                float ni = pr * ai + pi * ar;
                pr = nr; pi = ni;
            }
            Uo[cc * 2 + 0] = pr;
            Uo[cc * 2 + 1] = pi;
        }
        return;
    }

    // ---- conv1 path ----
    int bid = blk - 1528;
    int tile = bid & 255;
    int b = bid >> 8;
    int tx0 = (tile & 7) * 32, ty0 = (tile >> 3) * 8;

    for (int i = tid; i < 288; i += 256) s_w[i] = wt[i];
    for (int i = tid; i < 340; i += 256) {
        int yy = i / 34, xx = i % 34;
        int gy = ty0 + yy - 1, gx = tx0 + xx - 1;
        float v = 0.f;
        if (gy >= 0 && gy < 256 && gx >= 0 && gx < 256)
            v = x[(size_t)b * 65536 + gy * 256 + gx];
        s_in[yy][xx] = v;
    }
    __syncthreads();

    int px = tid & 31, py = tid >> 5;
    float t[3][3];
#pragma unroll
    for (int i = 0; i < 3; ++i)
#pragma unroll
        for (int j = 0; j < 3; ++j) t[i][j] = s_in[py + i][px + j];

    bool wr_pool = ((px & 1) == 0) && ((py & 1) == 0);
    ushort ph[32], pl[32];

    size_t obase = ((size_t)b * 32) * 65536 + (size_t)(ty0 + py) * 256 + (tx0 + px);
#pragma unroll 4
    for (int oc = 0; oc < 32; ++oc) {
        const float* wr = &s_w[oc * 9];
        float s = wr[0]*t[0][0] + wr[1]*t[0][1] + wr[2]*t[0][2]
                + wr[3]*t[1][0] + wr[4]*t[1][1] + wr[5]*t[1][2]
                + wr[6]*t[2][0] + wr[7]*t[2][1] + wr[8]*t[2][2];
        s = s * (g[oc] * BN_INV) + be[oc];
        s = fmaxf(s, 0.f);
        out[obase + (size_t)oc * 65536] = s;
        float p = fmaxf(s, __shfl_xor(s, 1));   // x-pair
        p = fmaxf(p, __shfl_xor(p, 32));        // y-pair (rows are tid>>5)
        fsplit(p, ph[oc], pl[oc]);
    }
    if (wr_pool) {
        ushort* op = pooled + (((size_t)b * 128 + ((ty0 + py) >> 1)) * 128 + ((tx0 + px) >> 1)) * 64;
#pragma unroll
        for (int k = 0; k < 4; ++k) {
            uint4 u;
            u.x = (uint)ph[8*k+0] | ((uint)ph[8*k+1] << 16);
            u.y = (uint)ph[8*k+2] | ((uint)ph[8*k+3] << 16);
            u.z = (uint)ph[8*k+4] | ((uint)ph[8*k+5] << 16);
            u.w = (uint)ph[8*k+6] | ((uint)ph[8*k+7] << 16);
            *(uint4*)(op + 8 * k) = u;
            uint4 v;
            v.x = (uint)pl[8*k+0] | ((uint)pl[8*k+1] << 16);
            v.y = (uint)pl[8*k+2] | ((uint)pl[8*k+3] << 16);
            v.z = (uint)pl[8*k+4] | ((uint)pl[8*k+5] << 16);
            v.w = (uint)pl[8*k+6] | ((uint)pl[8*k+7] << 16);
            *(uint4*)(op + 32 + 8 * k) = v;
        }
    }
}

// ---------------------------------------------------------------------------
// Split-fp16 MFMA implicit-GEMM 3x3 conv + BN + ReLU, optional fused pool.
// Tile: 64 oc x 128 sites (16 wide x 8 tall); 8 waves (512 threads) =
// 2 oc-halves x 4 site-groups (2 rows each). Per wave per tap: 4 global
// A-frag loads (L2-hot weights), 4 ds_read_b128 B-frags, 12 MFMA.
// Double-buffered LDS input staging: stage chunk ch+1 while computing ch
// (one barrier per K-chunk, loads in flight across the MFMA phase).
// acc += Wh*Bh + Wh*Bl + Wl*Bh (err ~2^-22).
// XCD-bijective blockIdx swizzle for L2 locality (grid % 8 == 0).
// ---------------------------------------------------------------------------
template <int CIN, int COUT, int HW, bool POOL>
__global__ __launch_bounds__(512) void conv3x3_mfma_split(
    const ushort* __restrict__ in,   // (8,HW,HW,2*CIN)
    const ushort* __restrict__ wb,   // packed split
    const float* __restrict__ g, const float* __restrict__ be,
    float* __restrict__ out,         // (8,COUT,HW,HW) fp32
    ushort* __restrict__ pooled)     // (8,HW/2,HW/2,2*COUT) if POOL
{
    constexpr int NCH = CIN / 32;
    constexpr int NTX = HW / 16;
    constexpr int NT = NTX * (HW / 8);
    constexpr int NOCG = COUT / 64;
    constexpr int PS = 72;
    constexpr int BUFSZ = 180 * PS;          // 12960 ushorts = 25920 B
    constexpr int NBUF = (NCH > 1) ? 2 : 1;

    __shared__ __align__(16) ushort s_in[NBUF * BUFSZ];

    constexpr int NWG = NT * NOCG * 8;
    int bid = blockIdx.x;
    bid = (bid & 7) * (NWG >> 3) + (bid >> 3);   // XCD-bijective swizzle

    int tile = bid % NT;
    int rest = bid / NT;
    int ocg = rest % NOCG;
    int b = rest / NOCG;
    int x0 = (tile % NTX) * 16;
    int y0 = (tile / NTX) * 8;

    int tid = threadIdx.x;
    int wv = tid >> 6;           // 0..7
    int lane = tid & 63;
    int n = lane & 15;
    int q = lane >> 4;
    int oc_half = (wv & 1) * 32;
    int sg = wv >> 1;            // site-group: rows sg*2, sg*2+1

    int ib[2];
#pragma unroll
    for (int f = 0; f < 2; ++f)
        ib[f] = ((sg * 2 + f) * 18 + n) * PS + q * 8;
    int iwa0 = q * 512 + (oc_half + n) * 8;
    int iwa1 = q * 512 + (oc_half + 16 + n) * 8;

    const ushort* inb = in + (size_t)b * HW * HW * 2 * CIN;

    f4v acc[2][2];
#pragma unroll
    for (int a = 0; a < 2; ++a)
#pragma unroll
        for (int f = 0; f < 2; ++f) acc[a][f] = (f4v){0.f, 0.f, 0.f, 0.f};

    // stage input halo chunk `ch` into buffer `bsel`:
    // 180 pos x {hi,lo} x 8 uint2-units (4 ic each)
    auto stage = [&](int ch, int bsel) {
#pragma unroll
        for (int it = 0; it < 6; ++it) {
            int i = tid + it * 512;
            if (i < 2880) {
                int pos = i >> 4;
                int r2 = i & 15;
                int comp = r2 >> 3;
                int u = r2 & 7;
                int py = pos / 18, px = pos % 18;
                int gy = y0 - 1 + py, gx = x0 - 1 + px;
                uint2 v; v.x = 0u; v.y = 0u;
                if (gy >= 0 && gy < HW && gx >= 0 && gx < HW)
                    v = *(const uint2*)(inb + ((size_t)gy * HW + gx) * (2 * CIN)
                                        + comp * CIN + ch * 32 + u * 4);
                *(uint2*)(&s_in[bsel * BUFSZ + pos * PS + comp * 32 + u * 4]) = v;
            }
        }
    };

    stage(0, 0);
    int cur = 0;
    for (int ch = 0; ch < NCH; ++ch) {
        __syncthreads();                       // buf[cur] ready; prev reads done
        if (ch + 1 < NCH) stage(ch + 1, cur ^ 1);

        const ushort* wc = wb + (size_t)((ocg * NCH + ch) * 2) * 18432;
        const ushort* sb = &s_in[cur * BUFSZ];
        __builtin_amdgcn_s_setprio(1);
#pragma unroll 3
        for (int tap = 0; tap < 9; ++tap) {
            const int toff = ((tap / 3) * 18 + (tap % 3)) * PS;
            const ushort* wt_ = wc + tap * 2048;
            h8v ah0 = *(const h8v*)(wt_ + iwa0);
            h8v ah1 = *(const h8v*)(wt_ + iwa1);
            h8v al0 = *(const h8v*)(wt_ + 18432 + iwa0);
            h8v al1 = *(const h8v*)(wt_ + 18432 + iwa1);
            h8v bh[2], bl[2];
#pragma unroll
            for (int f = 0; f < 2; ++f) {
                bh[f] = *(const h8v*)(&sb[toff + ib[f]]);
                bl[f] = *(const h8v*)(&sb[toff + ib[f] + 32]);
            }
#pragma unroll
            for (int f = 0; f < 2; ++f) {
                acc[0][f] = __builtin_amdgcn_mfma_f32_16x16x32_f16(ah0, bh[f], acc[0][f], 0, 0, 0);
                acc[1][f] = __builtin_amdgcn_mfma_f32_16x16x32_f16(ah1, bh[f], acc[1][f], 0, 0, 0);
            }
#pragma unroll
            for (int f = 0; f < 2; ++f) {
                acc[0][f] = __builtin_amdgcn_mfma_f32_16x16x32_f16(ah0, bl[f], acc[0][f], 0, 0, 0);
                acc[1][f] = __builtin_amdgcn_mfma_f32_16x16x32_f16(ah1, bl[f], acc[1][f], 0, 0, 0);
            }
#pragma unroll
            for (int f = 0; f < 2; ++f) {
                acc[0][f] = __builtin_amdgcn_mfma_f32_16x16x32_f16(al0, bh[f], acc[0][f], 0, 0, 0);
                acc[1][f] = __builtin_amdgcn_mfma_f32_16x16x32_f16(al1, bh[f], acc[1][f], 0, 0, 0);
            }
        }
        __builtin_amdgcn_s_setprio(0);
        cur ^= (NBUF - 1);
    }

    // epilogue: D row = oc (q*4+r), col = site (n); y-row = sg*2+f, x = n
    float vr[2][2][4];
#pragma unroll
    for (int tf = 0; tf < 2; ++tf)
#pragma unroll
        for (int f = 0; f < 2; ++f) {
            int y = y0 + sg * 2 + f;
#pragma unroll
            for (int r = 0; r < 4; ++r) {
                int oc = ocg * 64 + oc_half + tf * 16 + q * 4 + r;
                float v = fmaxf(acc[tf][f][r] * (g[oc] * BN_INV) + be[oc], 0.f);
                vr[tf][f][r] = v;
                out[((size_t)(b * COUT + oc) * HW + y) * HW + (x0 + n)] = v;
            }
        }

    if (POOL) {
#pragma unroll
        for (int tf = 0; tf < 2; ++tf) {
            ushort h[4], l[4];
#pragma unroll
            for (int r = 0; r < 4; ++r) {
                float p = fmaxf(vr[tf][0][r], vr[tf][1][r]);
                p = fmaxf(p, __shfl_xor(p, 1));
                fsplit(p, h[r], l[r]);
            }
            if ((n & 1) == 0) {
                int pyp = (y0 >> 1) + sg;
                int pxp = (x0 + n) >> 1;
                int ocb = ocg * 64 + oc_half + tf * 16 + q * 4;
                ushort* op = pooled
                    + (((size_t)b * (HW / 2) + pyp) * (HW / 2) + pxp) * (2 * COUT);
                uint2 uh, ul;
                uh.x = (uint)h[0] | ((uint)h[1] << 16);
                uh.y = (uint)h[2] | ((uint)h[3] << 16);
                ul.x = (uint)l[0] | ((uint)l[1] << 16);
                ul.y = (uint)l[2] | ((uint)l[3] << 16);
                *(uint2*)(op + ocb) = uh;
                *(uint2*)(op + COUT + ocb) = ul;
            }
        }
    }
}

// ---------------------------------------------------------------------------
// Quantum stage + BN + ReLU (fp32). In-place safe (per-block plane).
// Padded 35x35 LDS plane (zero border) -> branch-free 4x4 patch extraction.
// Only the 10 rows with nonzero Z-mean are computed (popc==2 -> zm=0).
// ---------------------------------------------------------------------------
__global__ __launch_bounds__(256) void quantum_bn_relu(
    const float* __restrict__ e4,  // (8,256,32,32)
    const float* __restrict__ U,   // (256,16,16,2)
    const float* __restrict__ g5, const float* __restrict__ b5,
    float* __restrict__ out)       // (8,256,32,32)
{
    int blk = blockIdx.x;      // b*256 + c
    int c = blk & 255;
    __shared__ float sp[35][35];   // [yy+1][xx+1], yy,xx in -1..33
    __shared__ __align__(16) float sU[512];

    int tid = threadIdx.x;
    for (int i = tid; i < 1225; i += 256) ((float*)sp)[i] = 0.f;
    const float4* Usrc = (const float4*)(U + (size_t)c * 512);
    if (tid < 128) ((float4*)sU)[tid] = Usrc[tid];
    float4 pv = ((const float4*)(e4 + (size_t)blk * 1024))[tid];
    __syncthreads();
    {
        int y = tid >> 3, x4 = (tid & 7) << 2;
        sp[y + 1][x4 + 1] = pv.x;
        sp[y + 1][x4 + 2] = pv.y;
        sp[y + 1][x4 + 3] = pv.z;
        sp[y + 1][x4 + 4] = pv.w;
    }
    __syncthreads();

    float t[4][16];
    float inv2[4];
#pragma unroll
    for (int k = 0; k < 4; ++k) {
        int site = tid + 256 * k;
        int y = site >> 5, x = site & 31;
        float ss = 0.f;
#pragma unroll
        for (int i = 0; i < 4; ++i)
#pragma unroll
            for (int j = 0; j < 4; ++j) {
                float v = sp[y + i][x + j];   // (y+i-1)+1, (x+j-1)+1
                t[k][i * 4 + j] = v;
                ss += v * v;
            }
        float inv = 1.f / fmaxf(sqrtf(ss), 1e-12f);
        inv2[k] = inv * inv;
    }

    const int   RI[10] = {0, 1, 2, 4, 7, 8, 11, 13, 14, 15};
    const float ZM[10] = {1.f, .5f, .5f, .5f, -.5f, .5f, -.5f, -.5f, -.5f, -1.f};
    const float4* sU4 = (const float4*)sU;

    float s[4] = {0.f, 0.f, 0.f, 0.f};
#pragma unroll
    for (int ii = 0; ii < 10; ++ii) {
        int i = RI[ii];
        float re[4] = {0.f, 0.f, 0.f, 0.f};
        float im[4] = {0.f, 0.f, 0.f, 0.f};
#pragma unroll
        for (int jj = 0; jj < 8; ++jj) {
            float4 u = sU4[i * 8 + jj];
#pragma unroll
            for (int k = 0; k < 4; ++k) {
                re[k] += u.x * t[k][2 * jj];
                im[k] += u.y * t[k][2 * jj];
                re[k] += u.z * t[k][2 * jj + 1];
                im[k] += u.w * t[k][2 * jj + 1];
            }
        }
        float zm = ZM[ii];
#pragma unroll
        for (int k = 0; k < 4; ++k)
            s[k] += (re[k] * re[k] + im[k] * im[k]) * zm;
    }

    float sc = g5[c] * BN_INV, bi = b5[c];
#pragma unroll
    for (int k = 0; k < 4; ++k) {
        float q = (s[k] * inv2[k] + 1.f) * 0.5f;
        float o = fmaxf(q * sc + bi, 0.f);
        out[(size_t)blk * 1024 + tid + 256 * k] = o;
    }
}

// ---------------------------------------------------------------------------
extern "C" void kernel_launch(void* const* d_in, const int* in_sizes, int n_in,
                              void* d_out, int out_size, void* d_ws, size_t ws_size,
                              hipStream_t stream)
{
    const float* x   = (const float*)d_in[0];
    const float* w1  = (const float*)d_in[1];
    const float* g1  = (const float*)d_in[2];
    const float* b1  = (const float*)d_in[3];
    const float* w2  = (const float*)d_in[4];
    const float* g2  = (const float*)d_in[5];
    const float* b2  = (const float*)d_in[6];
    const float* w3  = (const float*)d_in[7];
    const float* g3  = (const float*)d_in[8];
    const float* b3  = (const float*)d_in[9];
    const float* w4  = (const float*)d_in[10];
    const float* g4  = (const float*)d_in[11];
    const float* b4  = (const float*)d_in[12];
    const float* qw0 = (const float*)d_in[13];
    const float* qw1 = (const float*)d_in[14];
    const float* g5  = (const float*)d_in[15];
    const float* b5  = (const float*)d_in[16];

    float* out = (float*)d_out;
    float* e1  = out;                         // 8*32*256*256 = 16777216
    float* e2  = out + 16777216;              // 8*64*128*128 =  8388608
    float* e3  = out + 25165824;              // 8*128*64*64  =  4194304
    float* o4  = out + 29360128;              // 8*256*32*32  =  2097152

    float* ws = (float*)d_ws;
    // floats: Uw@0(131072) wb2@131072(18432) wb3@149504(73728)
    // wb4@223232(294912) pt1@518144(4194304) pt2@4712448(2097152)
    // pt3 aliases pt1 (dead after conv2). Peak ~27.2 MB.
    float*  Uw  = ws;
    ushort* wb2 = (ushort*)(ws + 131072);
    ushort* wb3 = (ushort*)(ws + 149504);
    ushort* wb4 = (ushort*)(ws + 223232);
    ushort* pt1 = (ushort*)(ws + 518144);     // (8,128,128,64)
    ushort* pt2 = (ushort*)(ws + 4712448);    // (8,64,64,128)
    ushort* pt3 = (ushort*)(ws + 518144);     // (8,32,32,256), aliases pt1

    prep_conv1_kernel<<<1528 + 2048, 256, 0, stream>>>(
        qw0, qw1, Uw, w2, wb2, w3, wb3, w4, wb4,
        x, w1, g1, b1, e1, pt1);

    conv3x3_mfma_split<32, 64, 128, true><<<1024, 512, 0, stream>>>(pt1, wb2, g2, b2, e2, pt2);

    conv3x3_mfma_split<64, 128, 64, true><<<512, 512, 0, stream>>>(pt2, wb3, g3, b3, e3, pt3);

    conv3x3_mfma_split<128, 256, 32, false><<<256, 512, 0, stream>>>(pt3, wb4, g4, b4, o4, nullptr);

    quantum_bn_relu<<<2048, 256, 0, stream>>>(o4, Uw, g5, b5, o4);
}

// Round 2
// 246.753 us; speedup vs baseline: 1.2028x; 1.1395x over previous
//
#include <hip/hip_runtime.h>
#include <cstdint>
#include <cstddef>

#define BN_INV 0.9999950000374997f  /* 1/sqrt(1+1e-5) */

typedef __attribute__((ext_vector_type(8))) _Float16 h8v;
typedef __attribute__((ext_vector_type(4))) float f4v;

// split v = hi + lo, both fp16; residual <= 2^-22 * |v|
__device__ __forceinline__ void fsplit(float v, ushort& h, ushort& l) {
    _Float16 hh = (_Float16)v;
    _Float16 ll = (_Float16)(v - (float)hh);
    h = __builtin_bit_cast(ushort, hh);
    l = __builtin_bit_cast(ushort, ll);
}

// ---------------------------------------------------------------------------
// Repack helper: (O,I,3,3) fp32 -> split fp16 hi/lo planes, A-frag order.
// dst[(ocg*NCH+chunk)*2*18432 + comp*18432 + tap*2048 + q*512 + oc*8 + j],
// ic = chunk*32 + q*8 + j
// ---------------------------------------------------------------------------
__device__ __forceinline__ void repack_one(
    const float* __restrict__ w, ushort* __restrict__ dst, int CIN, int i)
{
    int ocf = i / (CIN * 9);
    int r = i % (CIN * 9);
    int ic = r / 9;
    int tap = r % 9;
    int ocg = ocf >> 6, oc = ocf & 63;
    int chunk = ic >> 5, q = (ic >> 3) & 3, j = ic & 7;
    int nch = CIN >> 5;
    ushort h, l;
    fsplit(w[i], h, l);
    size_t base = (size_t)((ocg * nch + chunk) * 2) * 18432
                + (size_t)tap * 2048 + q * 512 + oc * 8 + j;
    dst[base] = h;
    dst[base + 18432] = l;
}

// ---------------------------------------------------------------------------
// Fused prep + conv1.
// Blocks 0..2047: conv1 (1->32, 256x256) + BN + ReLU -> e1 fp32,
//   fused 2x2 pool -> split fp16 channel-last pt1 [b][128][128][hi32|lo32].
//   (conv1 first in dispatch order: it is the long pole of this kernel.)
// Blocks 2048..2063: build U. 2064..3575: repack w2/w3/w4.
// conv1 tile 32 wide x 8 tall: each wave (2 rows x 32 px) stores full
// 128 B rows of e1. oc loop FULLY unrolled: pooled-pack regs have static
// indices only (no scratch); weights padded to 12 floats/oc for b128 reads.
// ---------------------------------------------------------------------------
__global__ __launch_bounds__(256) void prep_conv1_kernel(
    const float* __restrict__ w0, const float* __restrict__ w1,
    float* __restrict__ U,
    const float* __restrict__ w2, ushort* __restrict__ wb2,
    const float* __restrict__ w3, ushort* __restrict__ wb3,
    const float* __restrict__ w4, ushort* __restrict__ wb4,
    const float* __restrict__ x, const float* __restrict__ wt,
    const float* __restrict__ g, const float* __restrict__ be,
    float* __restrict__ out, ushort* __restrict__ pooled)
{
    __shared__ float s_in[10][34];
    __shared__ float s_w[384];          // 32 oc x 12 (9 taps + 3 pad)

    int blk = blockIdx.x;
    int tid = threadIdx.x;

    if (blk >= 2048) {
        if (blk >= 2424)     { repack_one(w4, wb4, 128, (blk - 2424) * 256 + tid); return; }
        if (blk >= 2136)     { repack_one(w3, wb3,  64, (blk - 2136) * 256 + tid); return; }
        if (blk >= 2064)     { repack_one(w2, wb2,  32, (blk - 2064) * 256 + tid); return; }

        int idx = (blk - 2048) * 256 + tid;  // = c*16 + r
        int c = idx >> 4, r = idx & 15;
        float gr[4][2][2], gi[4][2][2];
        const float inv_sq2 = 0.70710678118654752f;
#pragma unroll
        for (int w = 0; w < 4; ++w) {
            float ty = w0[c * 2 + (w & 1)];
            float tz = w1[c * 2 + (w & 1)];
            float cy = cosf(0.5f * ty), sy = sinf(0.5f * ty);
            float cz = cosf(0.5f * tz), sz = sinf(0.5f * tz);
            float r00 = (cy - sy) * inv_sq2, r01 = (cy + sy) * inv_sq2;
            float r10 = (cy + sy) * inv_sq2, r11 = (sy - cy) * inv_sq2;
            gr[w][0][0] = cz * r00; gi[w][0][0] = -sz * r00;
            gr[w][0][1] = cz * r01; gi[w][0][1] = -sz * r01;
            gr[w][1][0] = cz * r10; gi[w][1][0] =  sz * r10;
            gr[w][1][1] = cz * r11; gi[w][1][1] =  sz * r11;
        }
        const int PTOT[16] = {0,13,3,14,6,11,5,8,12,1,15,2,10,7,9,4};
        int rp = PTOT[r];
        float* Uo = U + (size_t)c * 512 + r * 32;
#pragma unroll
        for (int cc = 0; cc < 16; ++cc) {
            float pr = 1.f, pi = 0.f;
#pragma unroll
            for (int w = 0; w < 4; ++w) {
                int ib = (rp >> (3 - w)) & 1, jb = (cc >> (3 - w)) & 1;
                float ar = gr[w][ib][jb], ai = gi[w][ib][jb];
                float nr = pr * ar - pi * ai;
                float ni = pr * ai + pi * ar;
                pr = nr; pi = ni;
            }
            Uo[cc * 2 + 0] = pr;
            Uo[cc * 2 + 1] = pi;
        }
        return;
    }

    // ---- conv1 path ----
    int bid = blk;
    int tile = bid & 255;
    int b = bid >> 8;
    int tx0 = (tile & 7) * 32, ty0 = (tile >> 3) * 8;

    for (int i = tid; i < 288; i += 256) s_w[(i / 9) * 12 + (i % 9)] = wt[i];
    for (int i = tid; i < 340; i += 256) {
        int yy = i / 34, xx = i % 34;
        int gy = ty0 + yy - 1, gx = tx0 + xx - 1;
        float v = 0.f;
        if (gy >= 0 && gy < 256 && gx >= 0 && gx < 256)
            v = x[(size_t)b * 65536 + gy * 256 + gx];
        s_in[yy][xx] = v;
    }
    __syncthreads();

    int px = tid & 31, py = tid >> 5;
    float t[3][3];
#pragma unroll
    for (int i = 0; i < 3; ++i)
#pragma unroll
        for (int j = 0; j < 3; ++j) t[i][j] = s_in[py + i][px + j];

    bool wr_pool = ((px & 1) == 0) && ((py & 1) == 0);
    ushort* op = pooled + (((size_t)b * 128 + ((ty0 + py) >> 1)) * 128 + ((tx0 + px) >> 1)) * 64;

    size_t obase = ((size_t)b * 32) * 65536 + (size_t)(ty0 + py) * 256 + (tx0 + px);
#pragma unroll
    for (int k = 0; k < 4; ++k) {
        uint4 uh, ul;
#pragma unroll
        for (int j = 0; j < 8; ++j) {
            const int oc = k * 8 + j;
            const float4 wa = *(const float4*)&s_w[oc * 12];
            const float4 wc = *(const float4*)&s_w[oc * 12 + 4];
            const float w8 = s_w[oc * 12 + 8];
            float s = wa.x * t[0][0] + wa.y * t[0][1] + wa.z * t[0][2]
                    + wa.w * t[1][0] + wc.x * t[1][1] + wc.y * t[1][2]
                    + wc.z * t[2][0] + wc.w * t[2][1] + w8  * t[2][2];
            s = s * (g[oc] * BN_INV) + be[oc];
            s = fmaxf(s, 0.f);
            out[obase + (size_t)oc * 65536] = s;
            float p = fmaxf(s, __shfl_xor(s, 1));   // x-pair
            p = fmaxf(p, __shfl_xor(p, 32));        // y-pair (rows are tid>>5)
            ushort h, l;
            fsplit(p, h, l);
            uint hw = (uint)h, lw = (uint)l;
            if (j == 0) { uh.x = hw; ul.x = lw; }
            else if (j == 1) { uh.x |= hw << 16; ul.x |= lw << 16; }
            else if (j == 2) { uh.y = hw; ul.y = lw; }
            else if (j == 3) { uh.y |= hw << 16; ul.y |= lw << 16; }
            else if (j == 4) { uh.z = hw; ul.z = lw; }
            else if (j == 5) { uh.z |= hw << 16; ul.z |= lw << 16; }
            else if (j == 6) { uh.w = hw; ul.w = lw; }
            else             { uh.w |= hw << 16; ul.w |= lw << 16; }
        }
        if (wr_pool) {
            *(uint4*)(op + 8 * k) = uh;
            *(uint4*)(op + 32 + 8 * k) = ul;
        }
    }
}

// ---------------------------------------------------------------------------
// Split-fp16 MFMA implicit-GEMM 3x3 conv + BN + ReLU, optional fused pool.
// Tile: 64 oc x 128 sites (16 wide x 8 tall); 8 waves (512 threads) =
// 2 oc-halves x 4 site-groups (2 rows each). Per wave per tap: 4 global
// A-frag loads (L2-hot weights), 4 ds_read_b128 B-frags, 12 MFMA.
// Double-buffered LDS input staging: stage chunk ch+1 while computing ch
// (one barrier per K-chunk, loads in flight across the MFMA phase).
// acc += Wh*Bh + Wh*Bl + Wl*Bh (err ~2^-22).
// XCD-bijective blockIdx swizzle for L2 locality (grid % 8 == 0).
// B-read bank profile: stride 144 B == 4 dwords mod 32 -> 64 lane-starts
// spread uniformly over all 8 16B slots -> 8/bank == conflict-free floor.
// ---------------------------------------------------------------------------
template <int CIN, int COUT, int HW, bool POOL>
__global__ __launch_bounds__(512) void conv3x3_mfma_split(
    const ushort* __restrict__ in,   // (8,HW,HW,2*CIN)
    const ushort* __restrict__ wb,   // packed split
    const float* __restrict__ g, const float* __restrict__ be,
    float* __restrict__ out,         // (8,COUT,HW,HW) fp32
    ushort* __restrict__ pooled)     // (8,HW/2,HW/2,2*COUT) if POOL
{
    constexpr int NCH = CIN / 32;
    constexpr int NTX = HW / 16;
    constexpr int NT = NTX * (HW / 8);
    constexpr int NOCG = COUT / 64;
    constexpr int PS = 72;
    constexpr int BUFSZ = 180 * PS;          // 12960 ushorts = 25920 B
    constexpr int NBUF = (NCH > 1) ? 2 : 1;

    __shared__ __align__(16) ushort s_in[NBUF * BUFSZ];

    constexpr int NWG = NT * NOCG * 8;
    int bid = blockIdx.x;
    bid = (bid & 7) * (NWG >> 3) + (bid >> 3);   // XCD-bijective swizzle

    int tile = bid % NT;
    int rest = bid / NT;
    int ocg = rest % NOCG;
    int b = rest / NOCG;
    int x0 = (tile % NTX) * 16;
    int y0 = (tile / NTX) * 8;

    int tid = threadIdx.x;
    int wv = tid >> 6;           // 0..7
    int lane = tid & 63;
    int n = lane & 15;
    int q = lane >> 4;
    int oc_half = (wv & 1) * 32;
    int sg = wv >> 1;            // site-group: rows sg*2, sg*2+1

    int ib[2];
#pragma unroll
    for (int f = 0; f < 2; ++f)
        ib[f] = ((sg * 2 + f) * 18 + n) * PS + q * 8;
    int iwa0 = q * 512 + (oc_half + n) * 8;
    int iwa1 = q * 512 + (oc_half + 16 + n) * 8;

    const ushort* inb = in + (size_t)b * HW * HW * 2 * CIN;

    f4v acc[2][2];
#pragma unroll
    for (int a = 0; a < 2; ++a)
#pragma unroll
        for (int f = 0; f < 2; ++f) acc[a][f] = (f4v){0.f, 0.f, 0.f, 0.f};

    // stage input halo chunk `ch` into buffer `bsel`:
    // 180 pos x {hi,lo} x 8 uint2-units (4 ic each)
    auto stage = [&](int ch, int bsel) {
#pragma unroll
        for (int it = 0; it < 6; ++it) {
            int i = tid + it * 512;
            if (i < 2880) {
                int pos = i >> 4;
                int r2 = i & 15;
                int comp = r2 >> 3;
                int u = r2 & 7;
                int py = pos / 18, px = pos % 18;
                int gy = y0 - 1 + py, gx = x0 - 1 + px;
                uint2 v; v.x = 0u; v.y = 0u;
                if (gy >= 0 && gy < HW && gx >= 0 && gx < HW)
                    v = *(const uint2*)(inb + ((size_t)gy * HW + gx) * (2 * CIN)
                                        + comp * CIN + ch * 32 + u * 4);
                *(uint2*)(&s_in[bsel * BUFSZ + pos * PS + comp * 32 + u * 4]) = v;
            }
        }
    };

    stage(0, 0);
    int cur = 0;
    for (int ch = 0; ch < NCH; ++ch) {
        __syncthreads();                       // buf[cur] ready; prev reads done
        if (ch + 1 < NCH) stage(ch + 1, cur ^ 1);

        const ushort* wc = wb + (size_t)((ocg * NCH + ch) * 2) * 18432;
        const ushort* sb = &s_in[cur * BUFSZ];
        __builtin_amdgcn_s_setprio(1);
#pragma unroll 3
        for (int tap = 0; tap < 9; ++tap) {
            const int toff = ((tap / 3) * 18 + (tap % 3)) * PS;
            const ushort* wt_ = wc + tap * 2048;
            h8v ah0 = *(const h8v*)(wt_ + iwa0);
            h8v ah1 = *(const h8v*)(wt_ + iwa1);
            h8v al0 = *(const h8v*)(wt_ + 18432 + iwa0);
            h8v al1 = *(const h8v*)(wt_ + 18432 + iwa1);
            h8v bh[2], bl[2];
#pragma unroll
            for (int f = 0; f < 2; ++f) {
                bh[f] = *(const h8v*)(&sb[toff + ib[f]]);
                bl[f] = *(const h8v*)(&sb[toff + ib[f] + 32]);
            }
#pragma unroll
            for (int f = 0; f < 2; ++f) {
                acc[0][f] = __builtin_amdgcn_mfma_f32_16x16x32_f16(ah0, bh[f], acc[0][f], 0, 0, 0);
                acc[1][f] = __builtin_amdgcn_mfma_f32_16x16x32_f16(ah1, bh[f], acc[1][f], 0, 0, 0);
            }
#pragma unroll
            for (int f = 0; f < 2; ++f) {
                acc[0][f] = __builtin_amdgcn_mfma_f32_16x16x32_f16(ah0, bl[f], acc[0][f], 0, 0, 0);
                acc[1][f] = __builtin_amdgcn_mfma_f32_16x16x32_f16(ah1, bl[f], acc[1][f], 0, 0, 0);
            }
#pragma unroll
            for (int f = 0; f < 2; ++f) {
                acc[0][f] = __builtin_amdgcn_mfma_f32_16x16x32_f16(al0, bh[f], acc[0][f], 0, 0, 0);
                acc[1][f] = __builtin_amdgcn_mfma_f32_16x16x32_f16(al1, bh[f], acc[1][f], 0, 0, 0);
            }
        }
        __builtin_amdgcn_s_setprio(0);
        cur ^= (NBUF - 1);
    }

    // epilogue: D row = oc (q*4+r), col = site (n); y-row = sg*2+f, x = n
    float vr[2][2][4];
#pragma unroll
    for (int tf = 0; tf < 2; ++tf)
#pragma unroll
        for (int f = 0; f < 2; ++f) {
            int y = y0 + sg * 2 + f;
#pragma unroll
            for (int r = 0; r < 4; ++r) {
                int oc = ocg * 64 + oc_half + tf * 16 + q * 4 + r;
                float v = fmaxf(acc[tf][f][r] * (g[oc] * BN_INV) + be[oc], 0.f);
                vr[tf][f][r] = v;
                out[((size_t)(b * COUT + oc) * HW + y) * HW + (x0 + n)] = v;
            }
        }

    if (POOL) {
#pragma unroll
        for (int tf = 0; tf < 2; ++tf) {
            ushort h[4], l[4];
#pragma unroll
            for (int r = 0; r < 4; ++r) {
                float p = fmaxf(vr[tf][0][r], vr[tf][1][r]);
                p = fmaxf(p, __shfl_xor(p, 1));
                fsplit(p, h[r], l[r]);
            }
            if ((n & 1) == 0) {
                int pyp = (y0 >> 1) + sg;
                int pxp = (x0 + n) >> 1;
                int ocb = ocg * 64 + oc_half + tf * 16 + q * 4;
                ushort* op = pooled
                    + (((size_t)b * (HW / 2) + pyp) * (HW / 2) + pxp) * (2 * COUT);
                uint2 uh, ul;
                uh.x = (uint)h[0] | ((uint)h[1] << 16);
                uh.y = (uint)h[2] | ((uint)h[3] << 16);
                ul.x = (uint)l[0] | ((uint)l[1] << 16);
                ul.y = (uint)l[2] | ((uint)l[3] << 16);
                *(uint2*)(op + ocb) = uh;
                *(uint2*)(op + COUT + ocb) = ul;
            }
        }
    }
}

// ---------------------------------------------------------------------------
// Quantum stage + BN + ReLU (fp32). In-place safe (per-block plane).
// Padded 35x35 LDS plane (zero border) -> branch-free 4x4 patch extraction.
// Only the 10 rows with nonzero Z-mean are computed (popc==2 -> zm=0).
// ---------------------------------------------------------------------------
__global__ __launch_bounds__(256) void quantum_bn_relu(
    const float* __restrict__ e4,  // (8,256,32,32)
    const float* __restrict__ U,   // (256,16,16,2)
    const float* __restrict__ g5, const float* __restrict__ b5,
    float* __restrict__ out)       // (8,256,32,32)
{
    int blk = blockIdx.x;      // b*256 + c
    int c = blk & 255;
    __shared__ float sp[35][35];   // [yy+1][xx+1], yy,xx in -1..33
    __shared__ __align__(16) float sU[512];

    int tid = threadIdx.x;
    for (int i = tid; i < 1225; i += 256) ((float*)sp)[i] = 0.f;
    const float4* Usrc = (const float4*)(U + (size_t)c * 512);
    if (tid < 128) ((float4*)sU)[tid] = Usrc[tid];
    float4 pv = ((const float4*)(e4 + (size_t)blk * 1024))[tid];
    __syncthreads();
    {
        int y = tid >> 3, x4 = (tid & 7) << 2;
        sp[y + 1][x4 + 1] = pv.x;
        sp[y + 1][x4 + 2] = pv.y;
        sp[y + 1][x4 + 3] = pv.z;
        sp[y + 1][x4 + 4] = pv.w;
    }
    __syncthreads();

    float t[4][16];
    float inv2[4];
#pragma unroll
    for (int k = 0; k < 4; ++k) {
        int site = tid + 256 * k;
        int y = site >> 5, x = site & 31;
        float ss = 0.f;
#pragma unroll
        for (int i = 0; i < 4; ++i)
#pragma unroll
            for (int j = 0; j < 4; ++j) {
                float v = sp[y + i][x + j];   // (y+i-1)+1, (x+j-1)+1
                t[k][i * 4 + j] = v;
                ss += v * v;
            }
        float inv = 1.f / fmaxf(sqrtf(ss), 1e-12f);
        inv2[k] = inv * inv;
    }

    const int   RI[10] = {0, 1, 2, 4, 7, 8, 11, 13, 14, 15};
    const float ZM[10] = {1.f, .5f, .5f, .5f, -.5f, .5f, -.5f, -.5f, -.5f, -1.f};
    const float4* sU4 = (const float4*)sU;

    float s[4] = {0.f, 0.f, 0.f, 0.f};
#pragma unroll
    for (int ii = 0; ii < 10; ++ii) {
        int i = RI[ii];
        float re[4] = {0.f, 0.f, 0.f, 0.f};
        float im[4] = {0.f, 0.f, 0.f, 0.f};
#pragma unroll
        for (int jj = 0; jj < 8; ++jj) {
            float4 u = sU4[i * 8 + jj];
#pragma unroll
            for (int k = 0; k < 4; ++k) {
                re[k] += u.x * t[k][2 * jj];
                im[k] += u.y * t[k][2 * jj];
                re[k] += u.z * t[k][2 * jj + 1];
                im[k] += u.w * t[k][2 * jj + 1];
            }
        }
        float zm = ZM[ii];
#pragma unroll
        for (int k = 0; k < 4; ++k)
            s[k] += (re[k] * re[k] + im[k] * im[k]) * zm;
    }

    float sc = g5[c] * BN_INV, bi = b5[c];
#pragma unroll
    for (int k = 0; k < 4; ++k) {
        float q = (s[k] * inv2[k] + 1.f) * 0.5f;
        float o = fmaxf(q * sc + bi, 0.f);
        out[(size_t)blk * 1024 + tid + 256 * k] = o;
    }
}

// ---------------------------------------------------------------------------
extern "C" void kernel_launch(void* const* d_in, const int* in_sizes, int n_in,
                              void* d_out, int out_size, void* d_ws, size_t ws_size,
                              hipStream_t stream)
{
    const float* x   = (const float*)d_in[0];
    const float* w1  = (const float*)d_in[1];
    const float* g1  = (const float*)d_in[2];
    const float* b1  = (const float*)d_in[3];
    const float* w2  = (const float*)d_in[4];
    const float* g2  = (const float*)d_in[5];
    const float* b2  = (const float*)d_in[6];
    const float* w3  = (const float*)d_in[7];
    const float* g3  = (const float*)d_in[8];
    const float* b3  = (const float*)d_in[9];
    const float* w4  = (const float*)d_in[10];
    const float* g4  = (const float*)d_in[11];
    const float* b4  = (const float*)d_in[12];
    const float* qw0 = (const float*)d_in[13];
    const float* qw1 = (const float*)d_in[14];
    const float* g5  = (const float*)d_in[15];
    const float* b5  = (const float*)d_in[16];

    float* out = (float*)d_out;
    float* e1  = out;                         // 8*32*256*256 = 16777216
    float* e2  = out + 16777216;              // 8*64*128*128 =  8388608
    float* e3  = out + 25165824;              // 8*128*64*64  =  4194304
    float* o4  = out + 29360128;              // 8*256*32*32  =  2097152

    float* ws = (float*)d_ws;
    // floats: Uw@0(131072) wb2@131072(18432) wb3@149504(73728)
    // wb4@223232(294912) pt1@518144(4194304) pt2@4712448(2097152)
    // pt3 aliases pt1 (dead after conv2). Peak ~27.2 MB.
    float*  Uw  = ws;
    ushort* wb2 = (ushort*)(ws + 131072);
    ushort* wb3 = (ushort*)(ws + 149504);
    ushort* wb4 = (ushort*)(ws + 223232);
    ushort* pt1 = (ushort*)(ws + 518144);     // (8,128,128,64)
    ushort* pt2 = (ushort*)(ws + 4712448);    // (8,64,64,128)
    ushort* pt3 = (ushort*)(ws + 518144);     // (8,32,32,256), aliases pt1

    prep_conv1_kernel<<<2048 + 1528, 256, 0, stream>>>(
        qw0, qw1, Uw, w2, wb2, w3, wb3, w4, wb4,
        x, w1, g1, b1, e1, pt1);

    conv3x3_mfma_split<32, 64, 128, true><<<1024, 512, 0, stream>>>(pt1, wb2, g2, b2, e2, pt2);

    conv3x3_mfma_split<64, 128, 64, true><<<512, 512, 0, stream>>>(pt2, wb3, g3, b3, e3, pt3);

    conv3x3_mfma_split<128, 256, 32, false><<<256, 512, 0, stream>>>(pt3, wb4, g4, b4, o4, nullptr);

    quantum_bn_relu<<<2048, 256, 0, stream>>>(o4, Uw, g5, b5, o4);
}